// Round 1
// baseline (427.316 us; speedup 1.0000x reference)
//
#include <hip/hip_runtime.h>
#include <math.h>

#define NN 50000
#define NE 800000
#define INF_DIM 256
#define HIDF 64
#define NC 32
#define SLOPE 0.2f

// ============================ CSR build ============================

__global__ void k_zero(int* __restrict__ counts){
  int i = blockIdx.x*blockDim.x + threadIdx.x;
  if(i < NN) counts[i] = 0;
}

__global__ void k_hist(const int* __restrict__ dst, int* __restrict__ counts){
  int e = blockIdx.x*blockDim.x + threadIdx.x;
  if(e < NE) atomicAdd(&counts[dst[e]], 1);
}

// 1024 elements per block (256 threads x 4). Writes per-block inclusive scan
// into rowstart[i+1]; block totals into blocksums.
__global__ void k_scan_a(const int* __restrict__ counts, int* __restrict__ rowstart,
                         int* __restrict__ blocksums){
  __shared__ int wsum[4];
  int tid = threadIdx.x;
  int idx = blockIdx.x*1024 + tid*4;
  int v0 = (idx+0<NN)?counts[idx+0]:0;
  int v1 = (idx+1<NN)?counts[idx+1]:0;
  int v2 = (idx+2<NN)?counts[idx+2]:0;
  int v3 = (idx+3<NN)?counts[idx+3]:0;
  int s0=v0, s1=s0+v1, s2=s1+v2, s3=s2+v3;
  int lane = tid & 63, w = tid >> 6;
  int x = s3;
  #pragma unroll
  for(int off=1; off<64; off<<=1){
    int y = __shfl_up(x, off, 64);
    if(lane >= off) x += y;
  }
  if(lane==63) wsum[w] = x;
  __syncthreads();
  int woff = 0;
  for(int i=0;i<w;i++) woff += wsum[i];
  int excl = woff + (x - s3);
  if(idx+0<NN) rowstart[idx+1] = excl + s0;
  if(idx+1<NN) rowstart[idx+2] = excl + s1;
  if(idx+2<NN) rowstart[idx+3] = excl + s2;
  if(idx+3<NN) rowstart[idx+4] = excl + s3;
  if(tid==0) blocksums[blockIdx.x] = wsum[0]+wsum[1]+wsum[2]+wsum[3];
}

__global__ void k_scan_b(const int* __restrict__ blocksums, int* __restrict__ blockoff){
  int lane = threadIdx.x;            // 64 threads, nb = 49 blocks to scan
  const int nb = (NN + 1023)/1024;
  int v = (lane<nb)? blocksums[lane] : 0;
  int x = v;
  #pragma unroll
  for(int off=1; off<64; off<<=1){
    int y = __shfl_up(x, off, 64);
    if(lane >= off) x += y;
  }
  if(lane<nb) blockoff[lane] = x - v;  // exclusive
}

__global__ void k_scan_c(const int* __restrict__ counts, int* __restrict__ rowstart,
                         const int* __restrict__ blockoff, int* __restrict__ cursor){
  int i = blockIdx.x*blockDim.x + threadIdx.x;
  if(i < NN){
    int incl = rowstart[i+1] + blockoff[i>>10];
    rowstart[i+1] = incl;
    cursor[i] = incl - counts[i];      // exclusive start, used by scatter
    if(i==0) rowstart[0] = 0;
  }
}

__global__ void k_scatter(const int* __restrict__ src, const int* __restrict__ dst,
                          int* __restrict__ cursor, int* __restrict__ ssrc){
  int e = blockIdx.x*blockDim.x + threadIdx.x;
  if(e < NE){
    int d = dst[e];
    int pos = atomicAdd(&cursor[d], 1);
    ssrc[pos] = src[e];
  }
}

// ============================ GEMM 1: h1 = x @ W1, fused a_src/a_dst dots ===

// block = 256 threads, 64 nodes per block. thread: cols (c, c+32), nodes 8i+r.
__global__ __launch_bounds__(256) void k_gemm1(
    const float* __restrict__ x, const float* __restrict__ W,
    const float* __restrict__ a_s, const float* __restrict__ a_d,
    float* __restrict__ h, float* __restrict__ as_o, float* __restrict__ ad_o){
  __shared__ float xs[64*64];   // [node][k] tile, 16 KB
  __shared__ float ws[64*64];   // [k][col]  tile, 16 KB
  int tid = threadIdx.x;
  int c = tid & 31;
  int r = tid >> 5;             // 0..7
  int nb0 = blockIdx.x * 64;
  float acc[8][2];
  #pragma unroll
  for(int i=0;i<8;i++){acc[i][0]=0.f;acc[i][1]=0.f;}

  for(int kt=0; kt<4; ++kt){
    #pragma unroll
    for(int j=0;j<4;j++){                       // x tile: 1024 float4
      int ft = tid + 256*j;
      int row = ft >> 4; int c4 = ft & 15;
      float4 v = make_float4(0.f,0.f,0.f,0.f);
      int gr = nb0 + row;
      if(gr < NN) v = *reinterpret_cast<const float4*>(&x[(size_t)gr*INF_DIM + kt*64 + c4*4]);
      *reinterpret_cast<float4*>(&xs[row*64 + c4*4]) = v;
    }
    #pragma unroll
    for(int j=0;j<4;j++){                       // W tile: contiguous 16 KB
      int ft = tid + 256*j;
      *reinterpret_cast<float4*>(&ws[ft*4]) =
          *reinterpret_cast<const float4*>(&W[kt*4096 + ft*4]);
    }
    __syncthreads();
    #pragma unroll
    for(int k4=0;k4<16;k4++){
      int k = k4*4;
      float w0a=ws[(k+0)*64+c],    w1a=ws[(k+1)*64+c],    w2a=ws[(k+2)*64+c],    w3a=ws[(k+3)*64+c];
      float w0b=ws[(k+0)*64+c+32], w1b=ws[(k+1)*64+c+32], w2b=ws[(k+2)*64+c+32], w3b=ws[(k+3)*64+c+32];
      #pragma unroll
      for(int i=0;i<8;i++){
        float4 xv = *reinterpret_cast<const float4*>(&xs[(8*i+r)*64 + k]);
        acc[i][0] += xv.x*w0a + xv.y*w1a + xv.z*w2a + xv.w*w3a;
        acc[i][1] += xv.x*w0b + xv.y*w1b + xv.z*w2b + xv.w*w3b;
      }
    }
    __syncthreads();
  }

  float a_s0 = a_s[c], a_s1 = a_s[c+32], a_d0 = a_d[c], a_d1 = a_d[c+32];
  #pragma unroll
  for(int i=0;i<8;i++){
    int n = nb0 + 8*i + r;
    if(n < NN){
      h[(size_t)n*HIDF + c]      = acc[i][0];
      h[(size_t)n*HIDF + c + 32] = acc[i][1];
    }
    float sv = acc[i][0]*a_s0 + acc[i][1]*a_s1;
    float dv = acc[i][0]*a_d0 + acc[i][1]*a_d1;
    #pragma unroll
    for(int mk=16; mk>=1; mk>>=1){              // reduce within 32-lane half
      sv += __shfl_xor(sv, mk, 64);
      dv += __shfl_xor(dv, mk, 64);
    }
    if(c==0 && n<NN){ as_o[n]=sv; ad_o[n]=dv; }
  }
}

// ============================ Aggregation layer 1 (64 feats, wave per node) =

__global__ __launch_bounds__(256) void k_agg1(
    const float* __restrict__ h1, const float* __restrict__ as1, const float* __restrict__ ad1,
    const int* __restrict__ rowstart, const int* __restrict__ ssrc,
    float* __restrict__ r1){
  int wv = threadIdx.x >> 6;
  int lane = threadIdx.x & 63;
  int n = blockIdx.x*4 + wv;       // grid exact: NN/4 blocks
  int rs = rowstart[n], re = rowstart[n+1];
  float adn = ad1[n];
  float m = -1e30f, l = 0.f, acc = 0.f;
  for(int e=rs; e<re; ++e){
    int s = ssrc[e];
    float z = as1[s] + adn;
    z = z > 0.f ? z : SLOPE*z;                   // leaky relu
    float nm = fmaxf(m, z);
    float scale = __expf(m - nm);
    float p = __expf(z - nm);
    l = l*scale + p;
    acc = acc*scale + p * h1[(size_t)s*HIDF + lane];
    m = nm;
  }
  float o = (l > 0.f) ? acc/l : 0.f;
  r1[(size_t)n*HIDF + lane] = fmaxf(o, 0.f);     // fused ReLU (layer-2 input)
}

// ============================ GEMM 2: h2 = r1 @ W2, fused a dots ============

__global__ __launch_bounds__(256) void k_gemm2(
    const float* __restrict__ r1, const float* __restrict__ W2,
    const float* __restrict__ a_s, const float* __restrict__ a_d,
    float* __restrict__ h2, float* __restrict__ as_o, float* __restrict__ ad_o){
  __shared__ float xs[32*64];   // 8 KB
  __shared__ float ws[64*32];   // 8 KB
  int tid = threadIdx.x;
  int c = tid & 31;
  int r = tid >> 5;             // 0..7
  int nb0 = blockIdx.x*32;
  #pragma unroll
  for(int j=0;j<2;j++){
    int ft = tid + 256*j;       // 512 float4 each array
    int row = ft >> 4; int c4 = ft & 15;
    float4 v = make_float4(0.f,0.f,0.f,0.f);
    int gr = nb0 + row;
    if(gr < NN) v = *reinterpret_cast<const float4*>(&r1[(size_t)gr*HIDF + c4*4]);
    *reinterpret_cast<float4*>(&xs[row*64 + c4*4]) = v;
    *reinterpret_cast<float4*>(&ws[ft*4]) = *reinterpret_cast<const float4*>(&W2[ft*4]);
  }
  __syncthreads();
  float acc[4] = {0.f,0.f,0.f,0.f};
  #pragma unroll
  for(int k4=0;k4<16;k4++){
    int k = k4*4;
    float w0=ws[(k+0)*32+c], w1=ws[(k+1)*32+c], w2=ws[(k+2)*32+c], w3=ws[(k+3)*32+c];
    #pragma unroll
    for(int i=0;i<4;i++){
      float4 xv = *reinterpret_cast<const float4*>(&xs[(8*i+r)*64 + k]);
      acc[i] += xv.x*w0 + xv.y*w1 + xv.z*w2 + xv.w*w3;
    }
  }
  float a_sc = a_s[c], a_dc = a_d[c];
  #pragma unroll
  for(int i=0;i<4;i++){
    int n = nb0 + 8*i + r;
    if(n<NN) h2[(size_t)n*NC + c] = acc[i];
    float sv = acc[i]*a_sc, dv = acc[i]*a_dc;
    #pragma unroll
    for(int mk=16; mk>=1; mk>>=1){
      sv += __shfl_xor(sv, mk, 64);
      dv += __shfl_xor(dv, mk, 64);
    }
    if(c==0 && n<NN){ as_o[n]=sv; ad_o[n]=dv; }
  }
}

// ============================ Aggregation layer 2 (32 feats, half-wave/node)

__global__ __launch_bounds__(256) void k_agg2(
    const float* __restrict__ h2, const float* __restrict__ as2, const float* __restrict__ ad2,
    const int* __restrict__ rowstart, const int* __restrict__ ssrc,
    float* __restrict__ out){
  int tid = threadIdx.x;
  int wv = tid >> 6;
  int lane = tid & 63;
  int half = lane >> 5;
  int c = lane & 31;
  int n = blockIdx.x*8 + wv*2 + half;   // grid exact: NN/8 blocks
  int rs = rowstart[n], re = rowstart[n+1];
  float adn = ad2[n];
  float m = -1e30f, l = 0.f, acc = 0.f;
  for(int e=rs; e<re; ++e){
    int s = ssrc[e];
    float z = as2[s] + adn;
    z = z > 0.f ? z : SLOPE*z;
    float nm = fmaxf(m, z);
    float scale = __expf(m - nm);
    float p = __expf(z - nm);
    l = l*scale + p;
    acc = acc*scale + p * h2[(size_t)s*NC + c];
    m = nm;
  }
  out[(size_t)n*NC + c] = (l > 0.f) ? acc/l : 0.f;
}

// ============================ launch ============================

extern "C" void kernel_launch(void* const* d_in, const int* in_sizes, int n_in,
                              void* d_out, int out_size, void* d_ws, size_t ws_size,
                              hipStream_t stream){
  const float* x   = (const float*)d_in[0];
  const int*   ei  = (const int*)d_in[1];
  const float* W1  = (const float*)d_in[2];
  const float* a1s = (const float*)d_in[3];
  const float* a1d = (const float*)d_in[4];
  const float* W2  = (const float*)d_in[5];
  const float* a2s = (const float*)d_in[6];
  const float* a2d = (const float*)d_in[7];
  const int* srcIdx = ei;         // edge_index[0]
  const int* dstIdx = ei + NE;    // edge_index[1]
  float* out = (float*)d_out;

  char* wsp = (char*)d_ws;
  size_t off = 0;
  auto alloc = [&](size_t bytes)->void*{
    void* p = wsp + off;
    off = (off + bytes + 255) & ~(size_t)255;
    return p;
  };
  int* counts    = (int*)alloc((size_t)NN*sizeof(int));
  int* rowstart  = (int*)alloc((size_t)(NN+1)*sizeof(int));
  int* cursor    = (int*)alloc((size_t)NN*sizeof(int));
  int* blocksums = (int*)alloc(64*sizeof(int));
  int* blockoff  = (int*)alloc(64*sizeof(int));
  int* ssrc      = (int*)alloc((size_t)NE*sizeof(int));
  float* h1      = (float*)alloc((size_t)NN*HIDF*sizeof(float));
  float* as1     = (float*)alloc((size_t)NN*sizeof(float));
  float* ad1     = (float*)alloc((size_t)NN*sizeof(float));
  float* r1      = (float*)alloc((size_t)NN*HIDF*sizeof(float));
  // layer-2 buffers alias layer-1 buffers that are dead after k_agg1
  float* h2  = h1;     // 50000*32 floats <= 50000*64 floats
  float* as2 = as1;
  float* ad2 = ad1;

  // CSR build (per launch — ws is re-poisoned every call)
  k_zero   <<<(NN+255)/256, 256, 0, stream>>>(counts);
  k_hist   <<<(NE+255)/256, 256, 0, stream>>>(dstIdx, counts);
  k_scan_a <<<(NN+1023)/1024, 256, 0, stream>>>(counts, rowstart, blocksums);
  k_scan_b <<<1, 64, 0, stream>>>(blocksums, blockoff);
  k_scan_c <<<(NN+255)/256, 256, 0, stream>>>(counts, rowstart, blockoff, cursor);
  k_scatter<<<(NE+255)/256, 256, 0, stream>>>(srcIdx, dstIdx, cursor, ssrc);

  // layer 1
  k_gemm1<<<(NN+63)/64, 256, 0, stream>>>(x, W1, a1s, a1d, h1, as1, ad1);
  k_agg1 <<<NN/4, 256, 0, stream>>>(h1, as1, ad1, rowstart, ssrc, r1);

  // layer 2
  k_gemm2<<<(NN+31)/32, 256, 0, stream>>>(r1, W2, a2s, a2d, h2, as2, ad2);
  k_agg2 <<<NN/8, 256, 0, stream>>>(h2, as2, ad2, rowstart, ssrc, out);
}

// Round 3
// 424.170 us; speedup vs baseline: 1.0074x; 1.0074x over previous
//
#include <hip/hip_runtime.h>
#include <math.h>

#define NN 50000
#define NE 800000
#define INF_DIM 256
#define HIDF 64
#define NC 32
#define SLOPE 0.2f

// ============================ CSR build ============================

__global__ void k_zero(int* __restrict__ counts){
  int i = blockIdx.x*blockDim.x + threadIdx.x;
  if(i < NN) counts[i] = 0;
}

__global__ void k_hist(const int* __restrict__ dst, int* __restrict__ counts){
  int e = blockIdx.x*blockDim.x + threadIdx.x;
  if(e < NE) atomicAdd(&counts[dst[e]], 1);
}

// 1024 elements per block (256 threads x 4). Writes per-block inclusive scan
// into rowstart[i+1]; block totals into blocksums.
__global__ void k_scan_a(const int* __restrict__ counts, int* __restrict__ rowstart,
                         int* __restrict__ blocksums){
  __shared__ int wsum[4];
  int tid = threadIdx.x;
  int idx = blockIdx.x*1024 + tid*4;
  int v0 = (idx+0<NN)?counts[idx+0]:0;
  int v1 = (idx+1<NN)?counts[idx+1]:0;
  int v2 = (idx+2<NN)?counts[idx+2]:0;
  int v3 = (idx+3<NN)?counts[idx+3]:0;
  int s0=v0, s1=s0+v1, s2=s1+v2, s3=s2+v3;
  int lane = tid & 63, w = tid >> 6;
  int x = s3;
  #pragma unroll
  for(int off=1; off<64; off<<=1){
    int y = __shfl_up(x, off, 64);
    if(lane >= off) x += y;
  }
  if(lane==63) wsum[w] = x;
  __syncthreads();
  int woff = 0;
  for(int i=0;i<w;i++) woff += wsum[i];
  int excl = woff + (x - s3);
  if(idx+0<NN) rowstart[idx+1] = excl + s0;
  if(idx+1<NN) rowstart[idx+2] = excl + s1;
  if(idx+2<NN) rowstart[idx+3] = excl + s2;
  if(idx+3<NN) rowstart[idx+4] = excl + s3;
  if(tid==0) blocksums[blockIdx.x] = wsum[0]+wsum[1]+wsum[2]+wsum[3];
}

__global__ void k_scan_b(const int* __restrict__ blocksums, int* __restrict__ blockoff){
  int lane = threadIdx.x;            // 64 threads, nb = 49 blocks to scan
  const int nb = (NN + 1023)/1024;
  int v = (lane<nb)? blocksums[lane] : 0;
  int x = v;
  #pragma unroll
  for(int off=1; off<64; off<<=1){
    int y = __shfl_up(x, off, 64);
    if(lane >= off) x += y;
  }
  if(lane<nb) blockoff[lane] = x - v;  // exclusive
}

__global__ void k_scan_c(const int* __restrict__ counts, int* __restrict__ rowstart,
                         const int* __restrict__ blockoff, int* __restrict__ cursor){
  int i = blockIdx.x*blockDim.x + threadIdx.x;
  if(i < NN){
    int incl = rowstart[i+1] + blockoff[i>>10];
    rowstart[i+1] = incl;
    cursor[i] = incl - counts[i];      // exclusive start, used by scatter
    if(i==0) rowstart[0] = 0;
  }
}

__global__ void k_scatter(const int* __restrict__ src, const int* __restrict__ dst,
                          int* __restrict__ cursor, int* __restrict__ ssrc){
  int e = blockIdx.x*blockDim.x + threadIdx.x;
  if(e < NE){
    int d = dst[e];
    int pos = atomicAdd(&cursor[d], 1);
    ssrc[pos] = src[e];
  }
}

// ============================ GEMM 1: h1 = x @ W1, fused a_src/a_dst dots ===
// 64 nodes x 64 cols per block, 256 threads, 4 nodes x 4 cols per thread.
// All LDS access is ds_read_b128/ds_write_b128; xs padded (LD=68) so the 4
// node-addresses per read land 4 banks apart (conflict-free). Staging is
// register-prefetched: load K-tile kt+1 into VGPRs while computing kt.
#define LDX 68

__global__ __launch_bounds__(256) void k_gemm1(
    const float* __restrict__ x, const float* __restrict__ W,
    const float* __restrict__ a_s, const float* __restrict__ a_d,
    float* __restrict__ h, float* __restrict__ as_o, float* __restrict__ ad_o){
  __shared__ float xs[64*LDX];   // [node][k], 17.4 KB
  __shared__ float ws[64*64];    // [k][col],  16 KB
  int tid = threadIdx.x;
  int tc = tid & 15;             // col group: cols tc*4 .. tc*4+3
  int tr = tid >> 4;             // 0..15
  int nb0 = blockIdx.x*64;

  float4 xr[4], wr[4];
  #pragma unroll
  for(int j=0;j<4;j++){
    int n = nb0 + tr + 16*j;
    xr[j] = (n<NN) ? *reinterpret_cast<const float4*>(&x[(size_t)n*INF_DIM + tc*4])
                   : make_float4(0.f,0.f,0.f,0.f);
    wr[j] = *reinterpret_cast<const float4*>(&W[(tr + 16*j)*64 + tc*4]);
  }

  float acc[4][4];
  #pragma unroll
  for(int i=0;i<4;i++){ acc[i][0]=0.f; acc[i][1]=0.f; acc[i][2]=0.f; acc[i][3]=0.f; }

  for(int kt=0; kt<4; ++kt){
    #pragma unroll
    for(int j=0;j<4;j++){
      *reinterpret_cast<float4*>(&xs[(tr+16*j)*LDX + tc*4]) = xr[j];
      *reinterpret_cast<float4*>(&ws[(tr+16*j)*64  + tc*4]) = wr[j];
    }
    __syncthreads();
    if(kt < 3){
      #pragma unroll
      for(int j=0;j<4;j++){
        int n = nb0 + tr + 16*j;
        xr[j] = (n<NN) ? *reinterpret_cast<const float4*>(&x[(size_t)n*INF_DIM + (kt+1)*64 + tc*4])
                       : make_float4(0.f,0.f,0.f,0.f);
        wr[j] = *reinterpret_cast<const float4*>(&W[((kt+1)*64 + tr + 16*j)*64 + tc*4]);
      }
    }
    #pragma unroll
    for(int k4=0;k4<16;k4++){
      int k = k4*4;
      float4 wv0 = *reinterpret_cast<const float4*>(&ws[(k+0)*64 + tc*4]);
      float4 wv1 = *reinterpret_cast<const float4*>(&ws[(k+1)*64 + tc*4]);
      float4 wv2 = *reinterpret_cast<const float4*>(&ws[(k+2)*64 + tc*4]);
      float4 wv3 = *reinterpret_cast<const float4*>(&ws[(k+3)*64 + tc*4]);
      #pragma unroll
      for(int i=0;i<4;i++){
        float4 xv = *reinterpret_cast<const float4*>(&xs[(tr+16*i)*LDX + k]);
        acc[i][0] += xv.x*wv0.x + xv.y*wv1.x + xv.z*wv2.x + xv.w*wv3.x;
        acc[i][1] += xv.x*wv0.y + xv.y*wv1.y + xv.z*wv2.y + xv.w*wv3.y;
        acc[i][2] += xv.x*wv0.z + xv.y*wv1.z + xv.z*wv2.z + xv.w*wv3.z;
        acc[i][3] += xv.x*wv0.w + xv.y*wv1.w + xv.z*wv2.w + xv.w*wv3.w;
      }
    }
    __syncthreads();
  }

  float4 as4 = *reinterpret_cast<const float4*>(&a_s[tc*4]);
  float4 ad4 = *reinterpret_cast<const float4*>(&a_d[tc*4]);
  #pragma unroll
  for(int i=0;i<4;i++){
    int n = nb0 + tr + 16*i;
    float sv = acc[i][0]*as4.x + acc[i][1]*as4.y + acc[i][2]*as4.z + acc[i][3]*as4.w;
    float dv = acc[i][0]*ad4.x + acc[i][1]*ad4.y + acc[i][2]*ad4.z + acc[i][3]*ad4.w;
    #pragma unroll
    for(int mk=1; mk<16; mk<<=1){        // reduce across the 16 tc-lanes
      sv += __shfl_xor(sv, mk, 64);
      dv += __shfl_xor(dv, mk, 64);
    }
    if(n < NN){
      *reinterpret_cast<float4*>(&h[(size_t)n*HIDF + tc*4]) =
          make_float4(acc[i][0],acc[i][1],acc[i][2],acc[i][3]);
      if(tc==0){ as_o[n]=sv; ad_o[n]=dv; }
    }
  }
}

// ============================ Aggregation layer 1 (64 feats, wave per node) =

__global__ __launch_bounds__(256) void k_agg1(
    const float* __restrict__ h1, const float* __restrict__ as1, const float* __restrict__ ad1,
    const int* __restrict__ rowstart, const int* __restrict__ ssrc,
    float* __restrict__ r1){
  int wv = threadIdx.x >> 6;
  int lane = threadIdx.x & 63;
  int n = blockIdx.x*4 + wv;       // grid exact: NN/4 blocks
  int rs = rowstart[n], re = rowstart[n+1];
  float adn = ad1[n];
  float m = -1e30f, l = 0.f, acc = 0.f;
  for(int e=rs; e<re; ++e){
    int s = ssrc[e];
    float z = as1[s] + adn;
    z = z > 0.f ? z : SLOPE*z;                   // leaky relu
    float nm = fmaxf(m, z);
    float scale = __expf(m - nm);
    float p = __expf(z - nm);
    l = l*scale + p;
    acc = acc*scale + p * h1[(size_t)s*HIDF + lane];
    m = nm;
  }
  float o = (l > 0.f) ? acc/l : 0.f;
  r1[(size_t)n*HIDF + lane] = fmaxf(o, 0.f);     // fused ReLU (layer-2 input)
}

// ============================ GEMM 2: h2 = r1 @ W2, fused a dots ============

__global__ __launch_bounds__(256) void k_gemm2(
    const float* __restrict__ r1, const float* __restrict__ W2,
    const float* __restrict__ a_s, const float* __restrict__ a_d,
    float* __restrict__ h2, float* __restrict__ as_o, float* __restrict__ ad_o){
  __shared__ float xs[32*64];   // 8 KB
  __shared__ float ws[64*32];   // 8 KB
  int tid = threadIdx.x;
  int c = tid & 31;
  int r = tid >> 5;             // 0..7
  int nb0 = blockIdx.x*32;
  #pragma unroll
  for(int j=0;j<2;j++){
    int ft = tid + 256*j;       // 512 float4 each array
    int row = ft >> 4; int c4 = ft & 15;
    float4 v = make_float4(0.f,0.f,0.f,0.f);
    int gr = nb0 + row;
    if(gr < NN) v = *reinterpret_cast<const float4*>(&r1[(size_t)gr*HIDF + c4*4]);
    *reinterpret_cast<float4*>(&xs[row*64 + c4*4]) = v;
    *reinterpret_cast<float4*>(&ws[ft*4]) = *reinterpret_cast<const float4*>(&W2[ft*4]);
  }
  __syncthreads();
  float acc[4] = {0.f,0.f,0.f,0.f};
  #pragma unroll
  for(int k4=0;k4<16;k4++){
    int k = k4*4;
    float w0=ws[(k+0)*32+c], w1=ws[(k+1)*32+c], w2=ws[(k+2)*32+c], w3=ws[(k+3)*32+c];
    #pragma unroll
    for(int i=0;i<4;i++){
      float4 xv = *reinterpret_cast<const float4*>(&xs[(8*i+r)*64 + k]);
      acc[i] += xv.x*w0 + xv.y*w1 + xv.z*w2 + xv.w*w3;
    }
  }
  float a_sc = a_s[c], a_dc = a_d[c];
  #pragma unroll
  for(int i=0;i<4;i++){
    int n = nb0 + 8*i + r;
    if(n<NN) h2[(size_t)n*NC + c] = acc[i];
    float sv = acc[i]*a_sc, dv = acc[i]*a_dc;
    #pragma unroll
    for(int mk=16; mk>=1; mk>>=1){
      sv += __shfl_xor(sv, mk, 64);
      dv += __shfl_xor(dv, mk, 64);
    }
    if(c==0 && n<NN){ as_o[n]=sv; ad_o[n]=dv; }
  }
}

// ============================ Aggregation layer 2 (32 feats, half-wave/node)

__global__ __launch_bounds__(256) void k_agg2(
    const float* __restrict__ h2, const float* __restrict__ as2, const float* __restrict__ ad2,
    const int* __restrict__ rowstart, const int* __restrict__ ssrc,
    float* __restrict__ out){
  int tid = threadIdx.x;
  int wv = tid >> 6;
  int lane = tid & 63;
  int half = lane >> 5;
  int c = lane & 31;
  int n = blockIdx.x*8 + wv*2 + half;   // grid exact: NN/8 blocks
  int rs = rowstart[n], re = rowstart[n+1];
  float adn = ad2[n];
  float m = -1e30f, l = 0.f, acc = 0.f;
  for(int e=rs; e<re; ++e){
    int s = ssrc[e];
    float z = as2[s] + adn;
    z = z > 0.f ? z : SLOPE*z;
    float nm = fmaxf(m, z);
    float scale = __expf(m - nm);
    float p = __expf(z - nm);
    l = l*scale + p;
    acc = acc*scale + p * h2[(size_t)s*NC + c];
    m = nm;
  }
  out[(size_t)n*NC + c] = (l > 0.f) ? acc/l : 0.f;
}

// ============================ launch ============================

extern "C" void kernel_launch(void* const* d_in, const int* in_sizes, int n_in,
                              void* d_out, int out_size, void* d_ws, size_t ws_size,
                              hipStream_t stream){
  const float* x   = (const float*)d_in[0];
  const int*   ei  = (const int*)d_in[1];
  const float* W1  = (const float*)d_in[2];
  const float* a1s = (const float*)d_in[3];
  const float* a1d = (const float*)d_in[4];
  const float* W2  = (const float*)d_in[5];
  const float* a2s = (const float*)d_in[6];
  const float* a2d = (const float*)d_in[7];
  const int* srcIdx = ei;         // edge_index[0]
  const int* dstIdx = ei + NE;    // edge_index[1]
  float* out = (float*)d_out;

  char* wsp = (char*)d_ws;
  size_t off = 0;
  auto alloc = [&](size_t bytes)->void*{
    void* p = wsp + off;
    off = (off + bytes + 255) & ~(size_t)255;
    return p;
  };
  int* counts    = (int*)alloc((size_t)NN*sizeof(int));
  int* rowstart  = (int*)alloc((size_t)(NN+1)*sizeof(int));
  int* cursor    = (int*)alloc((size_t)NN*sizeof(int));
  int* blocksums = (int*)alloc(64*sizeof(int));
  int* blockoff  = (int*)alloc(64*sizeof(int));
  int* ssrc      = (int*)alloc((size_t)NE*sizeof(int));
  float* h1      = (float*)alloc((size_t)NN*HIDF*sizeof(float));
  float* as1     = (float*)alloc((size_t)NN*sizeof(float));
  float* ad1     = (float*)alloc((size_t)NN*sizeof(float));
  float* r1      = (float*)alloc((size_t)NN*HIDF*sizeof(float));
  // layer-2 buffers alias layer-1 buffers that are dead after k_agg1
  float* h2  = h1;     // 50000*32 floats <= 50000*64 floats
  float* as2 = as1;
  float* ad2 = ad1;

  // CSR build (per launch — ws is re-poisoned every call)
  k_zero   <<<(NN+255)/256, 256, 0, stream>>>(counts);
  k_hist   <<<(NE+255)/256, 256, 0, stream>>>(dstIdx, counts);
  k_scan_a <<<(NN+1023)/1024, 256, 0, stream>>>(counts, rowstart, blocksums);
  k_scan_b <<<1, 64, 0, stream>>>(blocksums, blockoff);
  k_scan_c <<<(NN+255)/256, 256, 0, stream>>>(counts, rowstart, blockoff, cursor);
  k_scatter<<<(NE+255)/256, 256, 0, stream>>>(srcIdx, dstIdx, cursor, ssrc);

  // layer 1
  k_gemm1<<<(NN+63)/64, 256, 0, stream>>>(x, W1, a1s, a1d, h1, as1, ad1);
  k_agg1 <<<NN/4, 256, 0, stream>>>(h1, as1, ad1, rowstart, ssrc, r1);

  // layer 2
  k_gemm2<<<(NN+31)/32, 256, 0, stream>>>(r1, W2, a2s, a2d, h2, as2, ad2);
  k_agg2 <<<NN/8, 256, 0, stream>>>(h2, as2, ad2, rowstart, ssrc, out);
}

// Round 4
// 362.549 us; speedup vs baseline: 1.1786x; 1.1700x over previous
//
#include <hip/hip_runtime.h>
#include <math.h>

#define NN 50000
#define NE 800000
#define INF_DIM 256
#define HIDF 64
#define NC 32
#define SLOPE 0.2f

// ============================ CSR build ============================

__global__ void k_zero(int* __restrict__ counts){
  int i = blockIdx.x*blockDim.x + threadIdx.x;
  if(i < NN) counts[i] = 0;
}

__global__ void k_hist(const int* __restrict__ dst, int* __restrict__ counts){
  int e = blockIdx.x*blockDim.x + threadIdx.x;
  if(e < NE) atomicAdd(&counts[dst[e]], 1);
}

// 1024 elements per block (256 threads x 4). Per-block inclusive scan into
// rowstart[i+1]; block totals into blocksums.
__global__ void k_scan_a(const int* __restrict__ counts, int* __restrict__ rowstart,
                         int* __restrict__ blocksums){
  __shared__ int wsum[4];
  int tid = threadIdx.x;
  int idx = blockIdx.x*1024 + tid*4;
  int v0 = (idx+0<NN)?counts[idx+0]:0;
  int v1 = (idx+1<NN)?counts[idx+1]:0;
  int v2 = (idx+2<NN)?counts[idx+2]:0;
  int v3 = (idx+3<NN)?counts[idx+3]:0;
  int s0=v0, s1=s0+v1, s2=s1+v2, s3=s2+v3;
  int lane = tid & 63, w = tid >> 6;
  int x = s3;
  #pragma unroll
  for(int off=1; off<64; off<<=1){
    int y = __shfl_up(x, off, 64);
    if(lane >= off) x += y;
  }
  if(lane==63) wsum[w] = x;
  __syncthreads();
  int woff = 0;
  for(int i=0;i<w;i++) woff += wsum[i];
  int excl = woff + (x - s3);
  if(idx+0<NN) rowstart[idx+1] = excl + s0;
  if(idx+1<NN) rowstart[idx+2] = excl + s1;
  if(idx+2<NN) rowstart[idx+3] = excl + s2;
  if(idx+3<NN) rowstart[idx+4] = excl + s3;
  if(tid==0) blocksums[blockIdx.x] = wsum[0]+wsum[1]+wsum[2]+wsum[3];
}

__global__ void k_scan_b(const int* __restrict__ blocksums, int* __restrict__ blockoff){
  int lane = threadIdx.x;            // 64 threads, nb = 49 blocks to scan
  const int nb = (NN + 1023)/1024;
  int v = (lane<nb)? blocksums[lane] : 0;
  int x = v;
  #pragma unroll
  for(int off=1; off<64; off<<=1){
    int y = __shfl_up(x, off, 64);
    if(lane >= off) x += y;
  }
  if(lane<nb) blockoff[lane] = x - v;  // exclusive
}

__global__ void k_scan_c(const int* __restrict__ counts, int* __restrict__ rowstart,
                         const int* __restrict__ blockoff, int* __restrict__ cursor){
  int i = blockIdx.x*blockDim.x + threadIdx.x;
  if(i < NN){
    int incl = rowstart[i+1] + blockoff[i>>10];
    rowstart[i+1] = incl;
    cursor[i] = incl - counts[i];      // exclusive start, used by scatter
    if(i==0) rowstart[0] = 0;
  }
}

__global__ void k_scatter(const int* __restrict__ src, const int* __restrict__ dst,
                          int* __restrict__ cursor, int* __restrict__ ssrc){
  int e = blockIdx.x*blockDim.x + threadIdx.x;
  if(e < NE){
    int d = dst[e];
    int pos = atomicAdd(&cursor[d], 1);
    ssrc[pos] = src[e];
  }
}

// ============================ GEMM 1: h1 = x @ W1, fused a_src/a_dst dots ===
// Single-wave (64-thread) blocks, 64 nodes x 64 cols each, 8x8 per thread.
// Thread (ng=tid>>3, cg=tid&7) owns nodes {ng+8i} and cols {cg*8..cg*8+7}.
// xs pad LDXS=20: compute-read rows (ng+8i)*20 %32 = {0,20,8,28,16,4,24,12}
// -> 8 distinct bank groups, conflict-free b128 reads on the hot path.
#define LDXS 20

__global__ __launch_bounds__(64) void k_gemm1(
    const float* __restrict__ x, const float* __restrict__ W,
    const float* __restrict__ a_s, const float* __restrict__ a_d,
    float* __restrict__ h, float* __restrict__ as_o, float* __restrict__ ad_o){
  __shared__ float xs[64*LDXS];   // [node][k16] padded, 5.1 KB
  __shared__ float ws[16*64];     // [k16][col], 4 KB
  int tid = threadIdx.x;
  int ng = tid >> 3;              // 0..7
  int cg = tid & 7;               // 0..7
  int nb0 = blockIdx.x*64;

  int srow = nb0 + tid; if(srow > NN-1) srow = NN-1;   // stage row (clamped)
  const float* xrow = x + (size_t)srow*INF_DIM;
  int wrow = tid >> 2;            // 0..15
  int wcol = (tid & 3)*16;

  float4 xr[4], wr[4];
  #pragma unroll
  for(int j=0;j<4;j++){
    xr[j] = *reinterpret_cast<const float4*>(xrow + j*4);
    wr[j] = *reinterpret_cast<const float4*>(W + wrow*64 + wcol + j*4);
  }

  float4 acc0[8], acc1[8];
  #pragma unroll
  for(int i=0;i<8;i++){
    acc0[i] = make_float4(0.f,0.f,0.f,0.f);
    acc1[i] = make_float4(0.f,0.f,0.f,0.f);
  }

  for(int kt=0; kt<16; ++kt){
    #pragma unroll
    for(int j=0;j<4;j++){
      *reinterpret_cast<float4*>(xs + tid*LDXS + j*4) = xr[j];
      *reinterpret_cast<float4*>(ws + wrow*64 + wcol + j*4) = wr[j];
    }
    __syncthreads();
    if(kt < 15){
      #pragma unroll
      for(int j=0;j<4;j++){
        xr[j] = *reinterpret_cast<const float4*>(xrow + (kt+1)*16 + j*4);
        wr[j] = *reinterpret_cast<const float4*>(W + ((kt+1)*16 + wrow)*64 + wcol + j*4);
      }
    }
    #pragma unroll
    for(int k4=0;k4<4;k4++){
      int k = k4*4;
      float4 wa[4], wb[4];
      #pragma unroll
      for(int kk=0;kk<4;kk++){
        wa[kk] = *reinterpret_cast<const float4*>(ws + (k+kk)*64 + cg*8);
        wb[kk] = *reinterpret_cast<const float4*>(ws + (k+kk)*64 + cg*8 + 4);
      }
      #pragma unroll
      for(int i=0;i<8;i++){
        float4 xv = *reinterpret_cast<const float4*>(xs + (ng + 8*i)*LDXS + k);
        acc0[i].x += xv.x*wa[0].x + xv.y*wa[1].x + xv.z*wa[2].x + xv.w*wa[3].x;
        acc0[i].y += xv.x*wa[0].y + xv.y*wa[1].y + xv.z*wa[2].y + xv.w*wa[3].y;
        acc0[i].z += xv.x*wa[0].z + xv.y*wa[1].z + xv.z*wa[2].z + xv.w*wa[3].z;
        acc0[i].w += xv.x*wa[0].w + xv.y*wa[1].w + xv.z*wa[2].w + xv.w*wa[3].w;
        acc1[i].x += xv.x*wb[0].x + xv.y*wb[1].x + xv.z*wb[2].x + xv.w*wb[3].x;
        acc1[i].y += xv.x*wb[0].y + xv.y*wb[1].y + xv.z*wb[2].y + xv.w*wb[3].y;
        acc1[i].z += xv.x*wb[0].z + xv.y*wb[1].z + xv.z*wb[2].z + xv.w*wb[3].z;
        acc1[i].w += xv.x*wb[0].w + xv.y*wb[1].w + xv.z*wb[2].w + xv.w*wb[3].w;
      }
    }
    __syncthreads();
  }

  float4 asA = *reinterpret_cast<const float4*>(a_s + cg*8);
  float4 asB = *reinterpret_cast<const float4*>(a_s + cg*8 + 4);
  float4 adA = *reinterpret_cast<const float4*>(a_d + cg*8);
  float4 adB = *reinterpret_cast<const float4*>(a_d + cg*8 + 4);
  #pragma unroll
  for(int i=0;i<8;i++){
    int n = nb0 + ng + 8*i;
    float sv = acc0[i].x*asA.x + acc0[i].y*asA.y + acc0[i].z*asA.z + acc0[i].w*asA.w
             + acc1[i].x*asB.x + acc1[i].y*asB.y + acc1[i].z*asB.z + acc1[i].w*asB.w;
    float dv = acc0[i].x*adA.x + acc0[i].y*adA.y + acc0[i].z*adA.z + acc0[i].w*adA.w
             + acc1[i].x*adB.x + acc1[i].y*adB.y + acc1[i].z*adB.z + acc1[i].w*adB.w;
    #pragma unroll
    for(int mk=1; mk<8; mk<<=1){       // reduce across cg (lane bits 0-2)
      sv += __shfl_xor(sv, mk, 64);
      dv += __shfl_xor(dv, mk, 64);
    }
    if(n < NN){
      *reinterpret_cast<float4*>(h + (size_t)n*HIDF + cg*8)     = acc0[i];
      *reinterpret_cast<float4*>(h + (size_t)n*HIDF + cg*8 + 4) = acc1[i];
      if(cg==0){ as_o[n]=sv; ad_o[n]=dv; }
    }
  }
}

// ============================ Aggregation layer 1 ===========================
// Wave per node. Two-phase per 64-edge chunk: phase 1 edge-parallel across
// lanes (gather scores, shuffle-reduce max+sum, one rescale per chunk);
// phase 2 broadcast (s,p) via shfl + coalesced 256B h-row gather + fmac.

__global__ __launch_bounds__(256) void k_agg1(
    const float* __restrict__ h1, const float* __restrict__ as1, const float* __restrict__ ad1,
    const int* __restrict__ rowstart, const int* __restrict__ ssrc,
    float* __restrict__ r1){
  int wv = threadIdx.x >> 6;
  int lane = threadIdx.x & 63;
  int n = blockIdx.x*4 + wv;       // grid exact: NN/4 blocks
  int rs = rowstart[n], re = rowstart[n+1];
  float adn = ad1[n];
  float m = -1e30f, l = 0.f, acc = 0.f;
  for(int base=rs; base<re; base+=64){
    int cnt = re - base; if(cnt > 64) cnt = 64;
    int s = 0; float z = -1e30f;
    if(lane < cnt){
      s = ssrc[base+lane];
      float zz = as1[s] + adn;
      z = zz > 0.f ? zz : SLOPE*zz;              // leaky relu
    }
    float cm = z;
    #pragma unroll
    for(int off=32; off>=1; off>>=1) cm = fmaxf(cm, __shfl_xor(cm, off, 64));
    float nm = fmaxf(m, cm);
    float sc = __expf(m - nm);
    float p = (lane<cnt) ? __expf(z - nm) : 0.f;
    float cs = p;
    #pragma unroll
    for(int off=32; off>=1; off>>=1) cs += __shfl_xor(cs, off, 64);
    l = l*sc + cs;
    acc *= sc;
    for(int e=0; e<cnt; ++e){
      int   se = __shfl(s, e, 64);
      float pe = __shfl(p, e, 64);
      acc += pe * h1[(size_t)se*HIDF + lane];
    }
    m = nm;
  }
  float o = (l > 0.f) ? acc/l : 0.f;
  r1[(size_t)n*HIDF + lane] = fmaxf(o, 0.f);     // fused ReLU (layer-2 input)
}

// ============================ GEMM 2: h2 = r1 @ W2, fused a dots ============
// Single-wave blocks, 128 nodes x 32 cols, 8x8 per thread. W2 (8KB) fully
// LDS-resident; r1 read direct from L2 with depth-1 register prefetch.

__global__ __launch_bounds__(64) void k_gemm2(
    const float* __restrict__ r1, const float* __restrict__ W2,
    const float* __restrict__ a_s, const float* __restrict__ a_d,
    float* __restrict__ h2, float* __restrict__ as_o, float* __restrict__ ad_o){
  __shared__ float ws2[64*32];   // [k][c], 8 KB
  int tid = threadIdx.x;
  int ng = tid >> 2;             // 0..15
  int cg = tid & 3;              // 0..3
  int nb0 = blockIdx.x*128;
  #pragma unroll
  for(int j=0;j<8;j++)
    *reinterpret_cast<float4*>(ws2 + tid*32 + j*4) =
        *reinterpret_cast<const float4*>(W2 + tid*32 + j*4);
  __syncthreads();

  float4 acc0[8], acc1[8];
  #pragma unroll
  for(int i=0;i<8;i++){
    acc0[i] = make_float4(0.f,0.f,0.f,0.f);
    acc1[i] = make_float4(0.f,0.f,0.f,0.f);
  }

  float4 xc[8], xn[8];
  #pragma unroll
  for(int i=0;i<8;i++){
    int n = nb0 + ng + 16*i; if(n > NN-1) n = NN-1;
    xc[i] = *reinterpret_cast<const float4*>(r1 + (size_t)n*HIDF);
  }
  for(int k4=0;k4<16;k4++){
    if(k4 < 15){
      #pragma unroll
      for(int i=0;i<8;i++){
        int n = nb0 + ng + 16*i; if(n > NN-1) n = NN-1;
        xn[i] = *reinterpret_cast<const float4*>(r1 + (size_t)n*HIDF + (k4+1)*4);
      }
    }
    float4 wa[4], wb[4];
    #pragma unroll
    for(int kk=0;kk<4;kk++){
      wa[kk] = *reinterpret_cast<const float4*>(ws2 + (k4*4+kk)*32 + cg*8);
      wb[kk] = *reinterpret_cast<const float4*>(ws2 + (k4*4+kk)*32 + cg*8 + 4);
    }
    #pragma unroll
    for(int i=0;i<8;i++){
      float4 xv = xc[i];
      acc0[i].x += xv.x*wa[0].x + xv.y*wa[1].x + xv.z*wa[2].x + xv.w*wa[3].x;
      acc0[i].y += xv.x*wa[0].y + xv.y*wa[1].y + xv.z*wa[2].y + xv.w*wa[3].y;
      acc0[i].z += xv.x*wa[0].z + xv.y*wa[1].z + xv.z*wa[2].z + xv.w*wa[3].z;
      acc0[i].w += xv.x*wa[0].w + xv.y*wa[1].w + xv.z*wa[2].w + xv.w*wa[3].w;
      acc1[i].x += xv.x*wb[0].x + xv.y*wb[1].x + xv.z*wb[2].x + xv.w*wb[3].x;
      acc1[i].y += xv.x*wb[0].y + xv.y*wb[1].y + xv.z*wb[2].y + xv.w*wb[3].y;
      acc1[i].z += xv.x*wb[0].z + xv.y*wb[1].z + xv.z*wb[2].z + xv.w*wb[3].z;
      acc1[i].w += xv.x*wb[0].w + xv.y*wb[1].w + xv.z*wb[2].w + xv.w*wb[3].w;
    }
    #pragma unroll
    for(int i=0;i<8;i++) xc[i] = xn[i];
  }

  float4 asA = *reinterpret_cast<const float4*>(a_s + cg*8);
  float4 asB = *reinterpret_cast<const float4*>(a_s + cg*8 + 4);
  float4 adA = *reinterpret_cast<const float4*>(a_d + cg*8);
  float4 adB = *reinterpret_cast<const float4*>(a_d + cg*8 + 4);
  #pragma unroll
  for(int i=0;i<8;i++){
    int n = nb0 + ng + 16*i;
    float sv = acc0[i].x*asA.x + acc0[i].y*asA.y + acc0[i].z*asA.z + acc0[i].w*asA.w
             + acc1[i].x*asB.x + acc1[i].y*asB.y + acc1[i].z*asB.z + acc1[i].w*asB.w;
    float dv = acc0[i].x*adA.x + acc0[i].y*adA.y + acc0[i].z*adA.z + acc0[i].w*adA.w
             + acc1[i].x*adB.x + acc1[i].y*adB.y + acc1[i].z*adB.z + acc1[i].w*adB.w;
    #pragma unroll
    for(int mk=1; mk<4; mk<<=1){       // reduce across cg (lane bits 0-1)
      sv += __shfl_xor(sv, mk, 64);
      dv += __shfl_xor(dv, mk, 64);
    }
    if(n < NN){
      *reinterpret_cast<float4*>(h2 + (size_t)n*NC + cg*8)     = acc0[i];
      *reinterpret_cast<float4*>(h2 + (size_t)n*NC + cg*8 + 4) = acc1[i];
      if(cg==0){ as_o[n]=sv; ad_o[n]=dv; }
    }
  }
}

// ============================ Aggregation layer 2 ===========================
// Half-wave (32 lanes) per node, same two-phase scheme with width-32 ops.

__global__ __launch_bounds__(256) void k_agg2(
    const float* __restrict__ h2, const float* __restrict__ as2, const float* __restrict__ ad2,
    const int* __restrict__ rowstart, const int* __restrict__ ssrc,
    float* __restrict__ out){
  int tid = threadIdx.x;
  int sub = tid >> 5;              // 0..7 half-wave within block
  int c = tid & 31;
  int n = blockIdx.x*8 + sub;      // grid exact: NN/8 blocks
  int rs = rowstart[n], re = rowstart[n+1];
  float adn = ad2[n];
  float m = -1e30f, l = 0.f, acc = 0.f;
  for(int base=rs; base<re; base+=32){
    int cnt = re - base; if(cnt > 32) cnt = 32;
    int s = 0; float z = -1e30f;
    if(c < cnt){
      s = ssrc[base+c];
      float zz = as2[s] + adn;
      z = zz > 0.f ? zz : SLOPE*zz;
    }
    float cm = z;
    #pragma unroll
    for(int off=16; off>=1; off>>=1) cm = fmaxf(cm, __shfl_xor(cm, off, 32));
    float nm = fmaxf(m, cm);
    float sc = __expf(m - nm);
    float p = (c<cnt) ? __expf(z - nm) : 0.f;
    float cs = p;
    #pragma unroll
    for(int off=16; off>=1; off>>=1) cs += __shfl_xor(cs, off, 32);
    l = l*sc + cs;
    acc *= sc;
    for(int e=0; e<cnt; ++e){
      int   se = __shfl(s, e, 32);
      float pe = __shfl(p, e, 32);
      acc += pe * h2[(size_t)se*NC + c];
    }
    m = nm;
  }
  out[(size_t)n*NC + c] = (l > 0.f) ? acc/l : 0.f;
}

// ============================ launch ============================

extern "C" void kernel_launch(void* const* d_in, const int* in_sizes, int n_in,
                              void* d_out, int out_size, void* d_ws, size_t ws_size,
                              hipStream_t stream){
  const float* x   = (const float*)d_in[0];
  const int*   ei  = (const int*)d_in[1];
  const float* W1  = (const float*)d_in[2];
  const float* a1s = (const float*)d_in[3];
  const float* a1d = (const float*)d_in[4];
  const float* W2  = (const float*)d_in[5];
  const float* a2s = (const float*)d_in[6];
  const float* a2d = (const float*)d_in[7];
  const int* srcIdx = ei;         // edge_index[0]
  const int* dstIdx = ei + NE;    // edge_index[1]
  float* out = (float*)d_out;

  char* wsp = (char*)d_ws;
  size_t off = 0;
  auto alloc = [&](size_t bytes)->void*{
    void* p = wsp + off;
    off = (off + bytes + 255) & ~(size_t)255;
    return p;
  };
  int* counts    = (int*)alloc((size_t)NN*sizeof(int));
  int* rowstart  = (int*)alloc((size_t)(NN+1)*sizeof(int));
  int* cursor    = (int*)alloc((size_t)NN*sizeof(int));
  int* blocksums = (int*)alloc(64*sizeof(int));
  int* blockoff  = (int*)alloc(64*sizeof(int));
  int* ssrc      = (int*)alloc((size_t)NE*sizeof(int));
  float* h1      = (float*)alloc((size_t)NN*HIDF*sizeof(float));
  float* as1     = (float*)alloc((size_t)NN*sizeof(float));
  float* ad1     = (float*)alloc((size_t)NN*sizeof(float));
  float* r1      = (float*)alloc((size_t)NN*HIDF*sizeof(float));
  // layer-2 buffers alias layer-1 buffers that are dead after k_agg1
  float* h2  = h1;     // 50000*32 floats <= 50000*64 floats
  float* as2 = as1;
  float* ad2 = ad1;

  // CSR build (per launch — ws is re-poisoned every call)
  k_zero   <<<(NN+255)/256, 256, 0, stream>>>(counts);
  k_hist   <<<(NE+255)/256, 256, 0, stream>>>(dstIdx, counts);
  k_scan_a <<<(NN+1023)/1024, 256, 0, stream>>>(counts, rowstart, blocksums);
  k_scan_b <<<1, 64, 0, stream>>>(blocksums, blockoff);
  k_scan_c <<<(NN+255)/256, 256, 0, stream>>>(counts, rowstart, blockoff, cursor);
  k_scatter<<<(NE+255)/256, 256, 0, stream>>>(srcIdx, dstIdx, cursor, ssrc);

  // layer 1
  k_gemm1<<<(NN+63)/64, 64, 0, stream>>>(x, W1, a1s, a1d, h1, as1, ad1);
  k_agg1 <<<NN/4, 256, 0, stream>>>(h1, as1, ad1, rowstart, ssrc, r1);

  // layer 2
  k_gemm2<<<(NN+127)/128, 64, 0, stream>>>(r1, W2, a2s, a2d, h2, as2, ad2);
  k_agg2 <<<NN/8, 256, 0, stream>>>(h2, as2, ad2, rowstart, ssrc, out);
}

// Round 7
// 351.489 us; speedup vs baseline: 1.2157x; 1.0315x over previous
//
#include <hip/hip_runtime.h>
#include <math.h>

#define NN 50000
#define NE 800000
#define INF_DIM 256
#define HIDF 64
#define NC 32
#define SLOPE 0.2f

// ============================ CSR build ============================

__global__ void k_zero(int* __restrict__ counts){
  int i = blockIdx.x*blockDim.x + threadIdx.x;
  if(i < NN) counts[i] = 0;
}

__global__ void k_hist(const int* __restrict__ dst, int* __restrict__ counts){
  int e = blockIdx.x*blockDim.x + threadIdx.x;
  if(e < NE) atomicAdd(&counts[dst[e]], 1);
}

// 1024 elements per block (256 threads x 4). Per-block inclusive scan into
// rowstart[i+1]; block totals into blocksums.
__global__ void k_scan_a(const int* __restrict__ counts, int* __restrict__ rowstart,
                         int* __restrict__ blocksums){
  __shared__ int wsum[4];
  int tid = threadIdx.x;
  int idx = blockIdx.x*1024 + tid*4;
  int v0 = (idx+0<NN)?counts[idx+0]:0;
  int v1 = (idx+1<NN)?counts[idx+1]:0;
  int v2 = (idx+2<NN)?counts[idx+2]:0;
  int v3 = (idx+3<NN)?counts[idx+3]:0;
  int s0=v0, s1=s0+v1, s2=s1+v2, s3=s2+v3;
  int lane = tid & 63, w = tid >> 6;
  int x = s3;
  #pragma unroll
  for(int off=1; off<64; off<<=1){
    int y = __shfl_up(x, off, 64);
    if(lane >= off) x += y;
  }
  if(lane==63) wsum[w] = x;
  __syncthreads();
  int woff = 0;
  for(int i=0;i<w;i++) woff += wsum[i];
  int excl = woff + (x - s3);
  if(idx+0<NN) rowstart[idx+1] = excl + s0;
  if(idx+1<NN) rowstart[idx+2] = excl + s1;
  if(idx+2<NN) rowstart[idx+3] = excl + s2;
  if(idx+3<NN) rowstart[idx+4] = excl + s3;
  if(tid==0) blocksums[blockIdx.x] = wsum[0]+wsum[1]+wsum[2]+wsum[3];
}

__global__ void k_scan_b(const int* __restrict__ blocksums, int* __restrict__ blockoff){
  int lane = threadIdx.x;            // 64 threads, nb = 49 blocks to scan
  const int nb = (NN + 1023)/1024;
  int v = (lane<nb)? blocksums[lane] : 0;
  int x = v;
  #pragma unroll
  for(int off=1; off<64; off<<=1){
    int y = __shfl_up(x, off, 64);
    if(lane >= off) x += y;
  }
  if(lane<nb) blockoff[lane] = x - v;  // exclusive
}

__global__ void k_scan_c(const int* __restrict__ counts, int* __restrict__ rowstart,
                         const int* __restrict__ blockoff, int* __restrict__ cursor){
  int i = blockIdx.x*blockDim.x + threadIdx.x;
  if(i < NN){
    int incl = rowstart[i+1] + blockoff[i>>10];
    rowstart[i+1] = incl;
    cursor[i] = incl - counts[i];      // exclusive start, used by scatter
    if(i==0) rowstart[0] = 0;
  }
}

__global__ void k_scatter(const int* __restrict__ src, const int* __restrict__ dst,
                          int* __restrict__ cursor, int* __restrict__ ssrc){
  int e = blockIdx.x*blockDim.x + threadIdx.x;
  if(e < NE){
    int d = dst[e];
    int pos = atomicAdd(&cursor[d], 1);
    ssrc[pos] = src[e];
  }
}

// ============================ GEMM 1: h1 = x @ W1, fused a_src/a_dst dots ===
// lane = output row. acc = full 64-col row in 16 float4 VGPRs. x streamed
// per-lane (64 B per K-tile, depth-1 register prefetch). W indices are
// wave-uniform -> scalar loads (SGPR), FMA takes the SGPR operand. No LDS,
// no barriers, no shuffles. 782 independent single-wave blocks.

__global__ __launch_bounds__(64) void k_gemm1(
    const float* __restrict__ x, const float* __restrict__ W,
    const float* __restrict__ a_s, const float* __restrict__ a_d,
    float* __restrict__ h, float* __restrict__ as_o, float* __restrict__ ad_o){
  int lane = threadIdx.x;
  int n = blockIdx.x*64 + lane;
  int nr = (n < NN) ? n : (NN-1);
  const float* xrow = x + (size_t)nr*INF_DIM;
  const float4* Wv = reinterpret_cast<const float4*>(W);   // [256][16] float4

  float4 acc[16];
  #pragma unroll
  for(int i=0;i<16;i++) acc[i] = make_float4(0.f,0.f,0.f,0.f);

  float4 xc[4], xn[4];
  #pragma unroll
  for(int j=0;j<4;j++) xc[j] = *reinterpret_cast<const float4*>(xrow + j*4);

  for(int kt=0; kt<16; ++kt){
    if(kt < 15){
      #pragma unroll
      for(int j=0;j<4;j++)
        xn[j] = *reinterpret_cast<const float4*>(xrow + (kt+1)*16 + j*4);
    }
    #pragma unroll
    for(int k4=0;k4<4;k4++){
      int kbase = kt*16 + k4*4;          // uniform
      float4 xk = xc[k4];                // k-values kbase..kbase+3 of this row
      #pragma unroll
      for(int cb=0;cb<16;cb++){
        float4 w0 = Wv[(kbase+0)*16 + cb];   // uniform -> s_load
        float4 w1 = Wv[(kbase+1)*16 + cb];
        float4 w2 = Wv[(kbase+2)*16 + cb];
        float4 w3 = Wv[(kbase+3)*16 + cb];
        acc[cb].x += xk.x*w0.x + xk.y*w1.x + xk.z*w2.x + xk.w*w3.x;
        acc[cb].y += xk.x*w0.y + xk.y*w1.y + xk.z*w2.y + xk.w*w3.y;
        acc[cb].z += xk.x*w0.z + xk.y*w1.z + xk.z*w2.z + xk.w*w3.z;
        acc[cb].w += xk.x*w0.w + xk.y*w1.w + xk.z*w2.w + xk.w*w3.w;
      }
    }
    #pragma unroll
    for(int j=0;j<4;j++) xc[j] = xn[j];
  }

  const float4* asv = reinterpret_cast<const float4*>(a_s);
  const float4* adv = reinterpret_cast<const float4*>(a_d);
  float sv = 0.f, dv = 0.f;
  #pragma unroll
  for(int cb=0;cb<16;cb++){
    float4 a4 = asv[cb], d4 = adv[cb];
    sv += acc[cb].x*a4.x + acc[cb].y*a4.y + acc[cb].z*a4.z + acc[cb].w*a4.w;
    dv += acc[cb].x*d4.x + acc[cb].y*d4.y + acc[cb].z*d4.z + acc[cb].w*d4.w;
  }
  if(n < NN){
    #pragma unroll
    for(int cb=0;cb<16;cb++)
      *reinterpret_cast<float4*>(h + (size_t)n*HIDF + cb*4) = acc[cb];
    as_o[n] = sv; ad_o[n] = dv;
  }
}

// ============================ Aggregation layer 1 ===========================
// Wave per node, two-phase 64-edge chunks. Phase 1: edge-parallel scores,
// shuffle-reduce max+sum, one rescale per chunk. Phase 2: (s,p) pairs staged
// once in LDS, per-edge uniform ds_read_b64 broadcast + coalesced h-row fmac.

__global__ __launch_bounds__(256) void k_agg1(
    const float* __restrict__ h1, const float* __restrict__ as1, const float* __restrict__ ad1,
    const int* __restrict__ rowstart, const int* __restrict__ ssrc,
    float* __restrict__ r1){
  __shared__ int2 sp[4][64];
  int wv = threadIdx.x >> 6;
  int lane = threadIdx.x & 63;
  int n = blockIdx.x*4 + wv;       // grid exact: NN/4 blocks
  int rs = rowstart[n], re = rowstart[n+1];
  float adn = ad1[n];
  float m = -1e30f, l = 0.f, acc = 0.f;
  for(int base=rs; base<re; base+=64){
    int cnt = re - base; if(cnt > 64) cnt = 64;
    int s = 0; float z = -1e30f;
    if(lane < cnt){
      s = ssrc[base+lane];
      float zz = as1[s] + adn;
      z = zz > 0.f ? zz : SLOPE*zz;              // leaky relu
    }
    float cm = z;
    #pragma unroll
    for(int off=32; off>=1; off>>=1) cm = fmaxf(cm, __shfl_xor(cm, off, 64));
    float nm = fmaxf(m, cm);
    float sc = __expf(m - nm);
    float p = (lane<cnt) ? __expf(z - nm) : 0.f;
    float cs = p;
    #pragma unroll
    for(int off=32; off>=1; off>>=1) cs += __shfl_xor(cs, off, 64);
    l = l*sc + cs;
    acc *= sc;
    sp[wv][lane] = make_int2(s, __float_as_int(p));
    for(int e=0; e<cnt; ++e){
      int2 v = sp[wv][e];                        // uniform broadcast read
      acc += __int_as_float(v.y) * h1[(size_t)v.x*HIDF + lane];
    }
    m = nm;
  }
  float o = (l > 0.f) ? acc/l : 0.f;
  r1[(size_t)n*HIDF + lane] = fmaxf(o, 0.f);     // fused ReLU (layer-2 input)
}

// ============================ GEMM 2: h2 = r1 @ W2, fused a dots ============
// Same lane=row structure: acc = 32-col row in 8 float4, K=64, W2 via
// uniform scalar loads. No LDS, no barriers.

__global__ __launch_bounds__(64) void k_gemm2(
    const float* __restrict__ r1, const float* __restrict__ W2,
    const float* __restrict__ a_s, const float* __restrict__ a_d,
    float* __restrict__ h2, float* __restrict__ as_o, float* __restrict__ ad_o){
  int lane = threadIdx.x;
  int n = blockIdx.x*64 + lane;
  int nr = (n < NN) ? n : (NN-1);
  const float* xrow = r1 + (size_t)nr*HIDF;
  const float4* Wv = reinterpret_cast<const float4*>(W2);  // [64][8] float4

  float4 acc[8];
  #pragma unroll
  for(int i=0;i<8;i++) acc[i] = make_float4(0.f,0.f,0.f,0.f);

  float4 xc[4], xn[4];
  #pragma unroll
  for(int j=0;j<4;j++) xc[j] = *reinterpret_cast<const float4*>(xrow + j*4);

  for(int kt=0; kt<4; ++kt){
    if(kt < 3){
      #pragma unroll
      for(int j=0;j<4;j++)
        xn[j] = *reinterpret_cast<const float4*>(xrow + (kt+1)*16 + j*4);
    }
    #pragma unroll
    for(int k4=0;k4<4;k4++){
      int kbase = kt*16 + k4*4;          // uniform
      float4 xk = xc[k4];
      #pragma unroll
      for(int cb=0;cb<8;cb++){
        float4 w0 = Wv[(kbase+0)*8 + cb];
        float4 w1 = Wv[(kbase+1)*8 + cb];
        float4 w2 = Wv[(kbase+2)*8 + cb];
        float4 w3 = Wv[(kbase+3)*8 + cb];
        acc[cb].x += xk.x*w0.x + xk.y*w1.x + xk.z*w2.x + xk.w*w3.x;
        acc[cb].y += xk.x*w0.y + xk.y*w1.y + xk.z*w2.y + xk.w*w3.y;
        acc[cb].z += xk.x*w0.z + xk.y*w1.z + xk.z*w2.z + xk.w*w3.z;
        acc[cb].w += xk.x*w0.w + xk.y*w1.w + xk.z*w2.w + xk.w*w3.w;
      }
    }
    #pragma unroll
    for(int j=0;j<4;j++) xc[j] = xn[j];
  }

  const float4* asv = reinterpret_cast<const float4*>(a_s);
  const float4* adv = reinterpret_cast<const float4*>(a_d);
  float sv = 0.f, dv = 0.f;
  #pragma unroll
  for(int cb=0;cb<8;cb++){
    float4 a4 = asv[cb], d4 = adv[cb];
    sv += acc[cb].x*a4.x + acc[cb].y*a4.y + acc[cb].z*a4.z + acc[cb].w*a4.w;
    dv += acc[cb].x*d4.x + acc[cb].y*d4.y + acc[cb].z*d4.z + acc[cb].w*d4.w;
  }
  if(n < NN){
    #pragma unroll
    for(int cb=0;cb<8;cb++)
      *reinterpret_cast<float4*>(h2 + (size_t)n*NC + cb*4) = acc[cb];
    as_o[n] = sv; ad_o[n] = dv;
  }
}

// ============================ Aggregation layer 2 ===========================
// Half-wave (32 lanes) per node, same two-phase scheme, LDS (s,p) broadcast.

__global__ __launch_bounds__(256) void k_agg2(
    const float* __restrict__ h2, const float* __restrict__ as2, const float* __restrict__ ad2,
    const int* __restrict__ rowstart, const int* __restrict__ ssrc,
    float* __restrict__ out){
  __shared__ int2 sp2[8][32];
  int tid = threadIdx.x;
  int sub = tid >> 5;              // 0..7 half-wave within block
  int c = tid & 31;
  int n = blockIdx.x*8 + sub;      // grid exact: NN/8 blocks
  int rs = rowstart[n], re = rowstart[n+1];
  float adn = ad2[n];
  float m = -1e30f, l = 0.f, acc = 0.f;
  for(int base=rs; base<re; base+=32){
    int cnt = re - base; if(cnt > 32) cnt = 32;
    int s = 0; float z = -1e30f;
    if(c < cnt){
      s = ssrc[base+c];
      float zz = as2[s] + adn;
      z = zz > 0.f ? zz : SLOPE*zz;
    }
    float cm = z;
    #pragma unroll
    for(int off=16; off>=1; off>>=1) cm = fmaxf(cm, __shfl_xor(cm, off, 32));
    float nm = fmaxf(m, cm);
    float sc = __expf(m - nm);
    float p = (c<cnt) ? __expf(z - nm) : 0.f;
    float cs = p;
    #pragma unroll
    for(int off=16; off>=1; off>>=1) cs += __shfl_xor(cs, off, 32);
    l = l*sc + cs;
    acc *= sc;
    sp2[sub][c] = make_int2(s, __float_as_int(p));
    for(int e=0; e<cnt; ++e){
      int2 v = sp2[sub][e];
      acc += __int_as_float(v.y) * h2[(size_t)v.x*NC + c];
    }
    m = nm;
  }
  out[(size_t)n*NC + c] = (l > 0.f) ? acc/l : 0.f;
}

// ============================ launch ============================

extern "C" void kernel_launch(void* const* d_in, const int* in_sizes, int n_in,
                              void* d_out, int out_size, void* d_ws, size_t ws_size,
                              hipStream_t stream){
  const float* x   = (const float*)d_in[0];
  const int*   ei  = (const int*)d_in[1];
  const float* W1  = (const float*)d_in[2];
  const float* a1s = (const float*)d_in[3];
  const float* a1d = (const float*)d_in[4];
  const float* W2  = (const float*)d_in[5];
  const float* a2s = (const float*)d_in[6];
  const float* a2d = (const float*)d_in[7];
  const int* srcIdx = ei;         // edge_index[0]
  const int* dstIdx = ei + NE;    // edge_index[1]
  float* out = (float*)d_out;

  char* wsp = (char*)d_ws;
  size_t off = 0;
  auto alloc = [&](size_t bytes)->void*{
    void* p = wsp + off;
    off = (off + bytes + 255) & ~(size_t)255;
    return p;
  };
  int* counts    = (int*)alloc((size_t)NN*sizeof(int));
  int* rowstart  = (int*)alloc((size_t)(NN+1)*sizeof(int));
  int* cursor    = (int*)alloc((size_t)NN*sizeof(int));
  int* blocksums = (int*)alloc(64*sizeof(int));
  int* blockoff  = (int*)alloc(64*sizeof(int));
  int* ssrc      = (int*)alloc((size_t)NE*sizeof(int));
  float* h1      = (float*)alloc((size_t)NN*HIDF*sizeof(float));
  float* as1     = (float*)alloc((size_t)NN*sizeof(float));
  float* ad1     = (float*)alloc((size_t)NN*sizeof(float));
  float* r1      = (float*)alloc((size_t)NN*HIDF*sizeof(float));
  // layer-2 buffers alias layer-1 buffers that are dead after k_agg1
  float* h2  = h1;     // 50000*32 floats <= 50000*64 floats
  float* as2 = as1;
  float* ad2 = ad1;

  // CSR build (per launch — ws is re-poisoned every call)
  k_zero   <<<(NN+255)/256, 256, 0, stream>>>(counts);
  k_hist   <<<(NE+255)/256, 256, 0, stream>>>(dstIdx, counts);
  k_scan_a <<<(NN+1023)/1024, 256, 0, stream>>>(counts, rowstart, blocksums);
  k_scan_b <<<1, 64, 0, stream>>>(blocksums, blockoff);
  k_scan_c <<<(NN+255)/256, 256, 0, stream>>>(counts, rowstart, blockoff, cursor);
  k_scatter<<<(NE+255)/256, 256, 0, stream>>>(srcIdx, dstIdx, cursor, ssrc);

  // layer 1
  k_gemm1<<<(NN+63)/64, 64, 0, stream>>>(x, W1, a1s, a1d, h1, as1, ad1);
  k_agg1 <<<NN/4, 256, 0, stream>>>(h1, as1, ad1, rowstart, ssrc, r1);

  // layer 2
  k_gemm2<<<(NN+63)/64, 64, 0, stream>>>(r1, W2, a2s, a2d, h2, as2, ad2);
  k_agg2 <<<NN/8, 256, 0, stream>>>(h2, as2, ad2, rowstart, ssrc, out);
}

// Round 8
// 302.734 us; speedup vs baseline: 1.4115x; 1.1610x over previous
//
#include <hip/hip_runtime.h>
#include <math.h>

#define NN 50000
#define NE 800000
#define INF_DIM 256
#define HIDF 64
#define NC 32
#define SLOPE 0.2f

// ============================ CSR build ============================

__global__ void k_zero(int* __restrict__ counts){
  int i = blockIdx.x*blockDim.x + threadIdx.x;
  if(i < NN) counts[i] = 0;
}

__global__ void k_hist(const int* __restrict__ dst, int* __restrict__ counts){
  int e = blockIdx.x*blockDim.x + threadIdx.x;
  if(e < NE) atomicAdd(&counts[dst[e]], 1);
}

// 1024 elements per block (256 threads x 4). Per-block inclusive scan into
// rowstart[i+1]; block totals into blocksums.
__global__ void k_scan_a(const int* __restrict__ counts, int* __restrict__ rowstart,
                         int* __restrict__ blocksums){
  __shared__ int wsum[4];
  int tid = threadIdx.x;
  int idx = blockIdx.x*1024 + tid*4;
  int v0 = (idx+0<NN)?counts[idx+0]:0;
  int v1 = (idx+1<NN)?counts[idx+1]:0;
  int v2 = (idx+2<NN)?counts[idx+2]:0;
  int v3 = (idx+3<NN)?counts[idx+3]:0;
  int s0=v0, s1=s0+v1, s2=s1+v2, s3=s2+v3;
  int lane = tid & 63, w = tid >> 6;
  int x = s3;
  #pragma unroll
  for(int off=1; off<64; off<<=1){
    int y = __shfl_up(x, off, 64);
    if(lane >= off) x += y;
  }
  if(lane==63) wsum[w] = x;
  __syncthreads();
  int woff = 0;
  for(int i=0;i<w;i++) woff += wsum[i];
  int excl = woff + (x - s3);
  if(idx+0<NN) rowstart[idx+1] = excl + s0;
  if(idx+1<NN) rowstart[idx+2] = excl + s1;
  if(idx+2<NN) rowstart[idx+3] = excl + s2;
  if(idx+3<NN) rowstart[idx+4] = excl + s3;
  if(tid==0) blocksums[blockIdx.x] = wsum[0]+wsum[1]+wsum[2]+wsum[3];
}

__global__ void k_scan_b(const int* __restrict__ blocksums, int* __restrict__ blockoff){
  int lane = threadIdx.x;            // 64 threads, nb = 49 blocks to scan
  const int nb = (NN + 1023)/1024;
  int v = (lane<nb)? blocksums[lane] : 0;
  int x = v;
  #pragma unroll
  for(int off=1; off<64; off<<=1){
    int y = __shfl_up(x, off, 64);
    if(lane >= off) x += y;
  }
  if(lane<nb) blockoff[lane] = x - v;  // exclusive
}

__global__ void k_scan_c(const int* __restrict__ counts, int* __restrict__ rowstart,
                         const int* __restrict__ blockoff, int* __restrict__ cursor){
  int i = blockIdx.x*blockDim.x + threadIdx.x;
  if(i < NN){
    int incl = rowstart[i+1] + blockoff[i>>10];
    rowstart[i+1] = incl;
    cursor[i] = incl - counts[i];      // exclusive start, used by scatter
    if(i==0) rowstart[0] = 0;
  }
}

__global__ void k_scatter(const int* __restrict__ src, const int* __restrict__ dst,
                          int* __restrict__ cursor, int* __restrict__ ssrc){
  int e = blockIdx.x*blockDim.x + threadIdx.x;
  if(e < NE){
    int d = dst[e];
    int pos = atomicAdd(&cursor[d], 1);
    ssrc[pos] = src[e];
  }
}

// ============================ GEMM 1: h1 = x @ W1, fused a_src/a_dst dots ===
// 1-wave block, tile 32 nodes x 64 cols. Thread (ng=tid>>3, cg=tid&7):
// nodes {ng+8i, i<4}, cols {cg*8..cg*8+7}. x kept in per-lane registers
// (8 cg-lanes share a row -> coalescer broadcast-merge; x read once from HBM).
// LDS only stages W in 8-k slices (2 KB). Per k4: 8 ds_read_b128 (2-way = free)
// per 128 v_fma -> LDS caps VALU at ~67%. Grid 1563 blocks (~6 waves/CU).

__global__ __launch_bounds__(64) void k_gemm1(
    const float* __restrict__ x, const float* __restrict__ W,
    const float* __restrict__ a_s, const float* __restrict__ a_d,
    float* __restrict__ h, float* __restrict__ as_o, float* __restrict__ ad_o){
  __shared__ float ws[8*64];        // W slice [8k][64c], 2 KB
  float4* wsv = reinterpret_cast<float4*>(ws);
  const float4* Wv = reinterpret_cast<const float4*>(W);
  int tid = threadIdx.x;
  int ng = tid >> 3, cg = tid & 7;
  int nb0 = blockIdx.x*32;

  const float* xrow[4];
  #pragma unroll
  for(int i=0;i<4;i++){
    int n = nb0 + ng + 8*i;
    xrow[i] = x + (size_t)((n < NN) ? n : (NN-1))*INF_DIM;
  }

  float4 acc[4][2];
  #pragma unroll
  for(int i=0;i<4;i++){ acc[i][0]=make_float4(0.f,0.f,0.f,0.f); acc[i][1]=make_float4(0.f,0.f,0.f,0.f); }

  for(int st=0; st<32; ++st){
    int k0 = st*8;
    // stage W rows k0..k0+7 (128 float4, coalesced)
    wsv[tid]      = Wv[k0*16 + tid];
    wsv[tid + 64] = Wv[k0*16 + 64 + tid];
    // per-lane x for this 8-k slice: 4 rows x 2 float4
    float4 xa[4][2];
    #pragma unroll
    for(int i=0;i<4;i++){
      xa[i][0] = *reinterpret_cast<const float4*>(xrow[i] + k0);
      xa[i][1] = *reinterpret_cast<const float4*>(xrow[i] + k0 + 4);
    }
    __syncthreads();
    #pragma unroll
    for(int k4=0;k4<2;k4++){
      float4 wf[4][2];
      #pragma unroll
      for(int kk=0;kk<4;kk++){
        wf[kk][0] = wsv[(k4*4+kk)*16 + cg*2];
        wf[kk][1] = wsv[(k4*4+kk)*16 + cg*2 + 1];
      }
      #pragma unroll
      for(int i=0;i<4;i++){
        float4 xv = xa[i][k4];
        acc[i][0].x += xv.x*wf[0][0].x + xv.y*wf[1][0].x + xv.z*wf[2][0].x + xv.w*wf[3][0].x;
        acc[i][0].y += xv.x*wf[0][0].y + xv.y*wf[1][0].y + xv.z*wf[2][0].y + xv.w*wf[3][0].y;
        acc[i][0].z += xv.x*wf[0][0].z + xv.y*wf[1][0].z + xv.z*wf[2][0].z + xv.w*wf[3][0].z;
        acc[i][0].w += xv.x*wf[0][0].w + xv.y*wf[1][0].w + xv.z*wf[2][0].w + xv.w*wf[3][0].w;
        acc[i][1].x += xv.x*wf[0][1].x + xv.y*wf[1][1].x + xv.z*wf[2][1].x + xv.w*wf[3][1].x;
        acc[i][1].y += xv.x*wf[0][1].y + xv.y*wf[1][1].y + xv.z*wf[2][1].y + xv.w*wf[3][1].y;
        acc[i][1].z += xv.x*wf[0][1].z + xv.y*wf[1][1].z + xv.z*wf[2][1].z + xv.w*wf[3][1].z;
        acc[i][1].w += xv.x*wf[0][1].w + xv.y*wf[1][1].w + xv.z*wf[2][1].w + xv.w*wf[3][1].w;
      }
    }
    __syncthreads();
  }

  const float4* asv = reinterpret_cast<const float4*>(a_s);
  const float4* adv = reinterpret_cast<const float4*>(a_d);
  float4 asA = asv[cg*2], asB = asv[cg*2+1];
  float4 adA = adv[cg*2], adB = adv[cg*2+1];
  #pragma unroll
  for(int i=0;i<4;i++){
    int n = nb0 + ng + 8*i;
    float sv = acc[i][0].x*asA.x + acc[i][0].y*asA.y + acc[i][0].z*asA.z + acc[i][0].w*asA.w
             + acc[i][1].x*asB.x + acc[i][1].y*asB.y + acc[i][1].z*asB.z + acc[i][1].w*asB.w;
    float dv = acc[i][0].x*adA.x + acc[i][0].y*adA.y + acc[i][0].z*adA.z + acc[i][0].w*adA.w
             + acc[i][1].x*adB.x + acc[i][1].y*adB.y + acc[i][1].z*adB.z + acc[i][1].w*adB.w;
    #pragma unroll
    for(int mk=1; mk<8; mk<<=1){        // reduce across cg (lane bits 0-2)
      sv += __shfl_xor(sv, mk, 64);
      dv += __shfl_xor(dv, mk, 64);
    }
    if(n < NN){
      *reinterpret_cast<float4*>(h + (size_t)n*HIDF + cg*8)     = acc[i][0];
      *reinterpret_cast<float4*>(h + (size_t)n*HIDF + cg*8 + 4) = acc[i][1];
      if(cg==0){ as_o[n]=sv; ad_o[n]=dv; }
    }
  }
}

// ============================ Aggregation layer 1 ===========================
// Wave per node. Phase 1: 64 edges scored in parallel, shuffle-reduce
// max+sum, one rescale per chunk. Phase 2: (s,p) broadcast from registers
// via __shfl, gathers unrolled x4 so 4 L2 loads are in flight.

__global__ __launch_bounds__(256) void k_agg1(
    const float* __restrict__ h1, const float* __restrict__ as1, const float* __restrict__ ad1,
    const int* __restrict__ rowstart, const int* __restrict__ ssrc,
    float* __restrict__ r1){
  int lane = threadIdx.x & 63;
  int n = blockIdx.x*4 + (threadIdx.x >> 6);   // grid exact: NN/4 blocks
  int rs = rowstart[n], re = rowstart[n+1];
  float adn = ad1[n];
  float m = -1e30f, l = 0.f, acc = 0.f;
  for(int base=rs; base<re; base+=64){
    int cnt = re - base; if(cnt > 64) cnt = 64;
    int s = 0; float z = -1e30f;
    if(lane < cnt){
      s = ssrc[base+lane];
      float zz = as1[s] + adn;
      z = zz > 0.f ? zz : SLOPE*zz;              // leaky relu
    }
    float cm = z;
    #pragma unroll
    for(int off=32; off>=1; off>>=1) cm = fmaxf(cm, __shfl_xor(cm, off, 64));
    float nm = fmaxf(m, cm);
    float sc = __expf(m - nm);
    float p = (lane<cnt) ? __expf(z - nm) : 0.f;
    float cs = p;
    #pragma unroll
    for(int off=32; off>=1; off>>=1) cs += __shfl_xor(cs, off, 64);
    l = l*sc + cs;
    acc *= sc;
    int e = 0;
    for(; e+4<=cnt; e+=4){
      int   se0 = __shfl(s, e,   64), se1 = __shfl(s, e+1, 64);
      int   se2 = __shfl(s, e+2, 64), se3 = __shfl(s, e+3, 64);
      float pe0 = __shfl(p, e,   64), pe1 = __shfl(p, e+1, 64);
      float pe2 = __shfl(p, e+2, 64), pe3 = __shfl(p, e+3, 64);
      float v0 = h1[(size_t)se0*HIDF + lane];
      float v1 = h1[(size_t)se1*HIDF + lane];
      float v2 = h1[(size_t)se2*HIDF + lane];
      float v3 = h1[(size_t)se3*HIDF + lane];
      acc += pe0*v0; acc += pe1*v1; acc += pe2*v2; acc += pe3*v3;
    }
    for(; e<cnt; ++e){
      int   se = __shfl(s, e, 64);
      float pe = __shfl(p, e, 64);
      acc += pe * h1[(size_t)se*HIDF + lane];
    }
    m = nm;
  }
  float o = (l > 0.f) ? acc/l : 0.f;
  r1[(size_t)n*HIDF + lane] = fmaxf(o, 0.f);     // fused ReLU (layer-2 input)
}

// ============================ GEMM 2: h2 = r1 @ W2, fused a dots ============
// 1-wave block, tile 32 nodes x 32 cols, thread = 4 nodes x 4 cols.
// W2 (8 KB) fully LDS-resident, staged once. x per-lane registers.

__global__ __launch_bounds__(64) void k_gemm2(
    const float* __restrict__ r1, const float* __restrict__ W2,
    const float* __restrict__ a_s, const float* __restrict__ a_d,
    float* __restrict__ h2, float* __restrict__ as_o, float* __restrict__ ad_o){
  __shared__ float ws2[64*32];      // [64k][32c], 8 KB
  float4* wsv = reinterpret_cast<float4*>(ws2);
  const float4* Wv = reinterpret_cast<const float4*>(W2);
  int tid = threadIdx.x;
  int ng = tid >> 3, cg = tid & 7;
  int nb0 = blockIdx.x*32;
  #pragma unroll
  for(int j=0;j<8;j++) wsv[j*64 + tid] = Wv[j*64 + tid];   // 512 float4

  const float* xrow[4];
  #pragma unroll
  for(int i=0;i<4;i++){
    int n = nb0 + ng + 8*i;
    xrow[i] = r1 + (size_t)((n < NN) ? n : (NN-1))*HIDF;
  }
  float4 acc[4];
  #pragma unroll
  for(int i=0;i<4;i++) acc[i] = make_float4(0.f,0.f,0.f,0.f);
  __syncthreads();

  for(int st=0; st<8; ++st){
    int k0 = st*8;
    float4 xa[4][2];
    #pragma unroll
    for(int i=0;i<4;i++){
      xa[i][0] = *reinterpret_cast<const float4*>(xrow[i] + k0);
      xa[i][1] = *reinterpret_cast<const float4*>(xrow[i] + k0 + 4);
    }
    #pragma unroll
    for(int k4=0;k4<2;k4++){
      float4 wf[4];
      #pragma unroll
      for(int kk=0;kk<4;kk++) wf[kk] = wsv[(k0 + k4*4 + kk)*8 + cg];
      #pragma unroll
      for(int i=0;i<4;i++){
        float4 xv = xa[i][k4];
        acc[i].x += xv.x*wf[0].x + xv.y*wf[1].x + xv.z*wf[2].x + xv.w*wf[3].x;
        acc[i].y += xv.x*wf[0].y + xv.y*wf[1].y + xv.z*wf[2].y + xv.w*wf[3].y;
        acc[i].z += xv.x*wf[0].z + xv.y*wf[1].z + xv.z*wf[2].z + xv.w*wf[3].z;
        acc[i].w += xv.x*wf[0].w + xv.y*wf[1].w + xv.z*wf[2].w + xv.w*wf[3].w;
      }
    }
  }

  const float4* asv = reinterpret_cast<const float4*>(a_s);
  const float4* adv = reinterpret_cast<const float4*>(a_d);
  float4 as4 = asv[cg], ad4 = adv[cg];
  #pragma unroll
  for(int i=0;i<4;i++){
    int n = nb0 + ng + 8*i;
    float sv = acc[i].x*as4.x + acc[i].y*as4.y + acc[i].z*as4.z + acc[i].w*as4.w;
    float dv = acc[i].x*ad4.x + acc[i].y*ad4.y + acc[i].z*ad4.z + acc[i].w*ad4.w;
    #pragma unroll
    for(int mk=1; mk<8; mk<<=1){
      sv += __shfl_xor(sv, mk, 64);
      dv += __shfl_xor(dv, mk, 64);
    }
    if(n < NN){
      *reinterpret_cast<float4*>(h2 + (size_t)n*NC + cg*4) = acc[i];
      if(cg==0){ as_o[n]=sv; ad_o[n]=dv; }
    }
  }
}

// ============================ Aggregation layer 2 ===========================
// Half-wave (32 lanes) per node, same scheme, shfl broadcast + x4 unroll.

__global__ __launch_bounds__(256) void k_agg2(
    const float* __restrict__ h2, const float* __restrict__ as2, const float* __restrict__ ad2,
    const int* __restrict__ rowstart, const int* __restrict__ ssrc,
    float* __restrict__ out){
  int tid = threadIdx.x;
  int c = tid & 31;
  int n = blockIdx.x*8 + (tid >> 5);   // grid exact: NN/8 blocks
  int rs = rowstart[n], re = rowstart[n+1];
  float adn = ad2[n];
  float m = -1e30f, l = 0.f, acc = 0.f;
  for(int base=rs; base<re; base+=32){
    int cnt = re - base; if(cnt > 32) cnt = 32;
    int s = 0; float z = -1e30f;
    if(c < cnt){
      s = ssrc[base+c];
      float zz = as2[s] + adn;
      z = zz > 0.f ? zz : SLOPE*zz;
    }
    float cm = z;
    #pragma unroll
    for(int off=16; off>=1; off>>=1) cm = fmaxf(cm, __shfl_xor(cm, off, 32));
    float nm = fmaxf(m, cm);
    float sc = __expf(m - nm);
    float p = (c<cnt) ? __expf(z - nm) : 0.f;
    float cs = p;
    #pragma unroll
    for(int off=16; off>=1; off>>=1) cs += __shfl_xor(cs, off, 32);
    l = l*sc + cs;
    acc *= sc;
    int e = 0;
    for(; e+4<=cnt; e+=4){
      int   se0 = __shfl(s, e,   32), se1 = __shfl(s, e+1, 32);
      int   se2 = __shfl(s, e+2, 32), se3 = __shfl(s, e+3, 32);
      float pe0 = __shfl(p, e,   32), pe1 = __shfl(p, e+1, 32);
      float pe2 = __shfl(p, e+2, 32), pe3 = __shfl(p, e+3, 32);
      float v0 = h2[(size_t)se0*NC + c];
      float v1 = h2[(size_t)se1*NC + c];
      float v2 = h2[(size_t)se2*NC + c];
      float v3 = h2[(size_t)se3*NC + c];
      acc += pe0*v0; acc += pe1*v1; acc += pe2*v2; acc += pe3*v3;
    }
    for(; e<cnt; ++e){
      int   se = __shfl(s, e, 32);
      float pe = __shfl(p, e, 32);
      acc += pe * h2[(size_t)se*NC + c];
    }
    m = nm;
  }
  out[(size_t)n*NC + c] = (l > 0.f) ? acc/l : 0.f;
}

// ============================ launch ============================

extern "C" void kernel_launch(void* const* d_in, const int* in_sizes, int n_in,
                              void* d_out, int out_size, void* d_ws, size_t ws_size,
                              hipStream_t stream){
  const float* x   = (const float*)d_in[0];
  const int*   ei  = (const int*)d_in[1];
  const float* W1  = (const float*)d_in[2];
  const float* a1s = (const float*)d_in[3];
  const float* a1d = (const float*)d_in[4];
  const float* W2  = (const float*)d_in[5];
  const float* a2s = (const float*)d_in[6];
  const float* a2d = (const float*)d_in[7];
  const int* srcIdx = ei;         // edge_index[0]
  const int* dstIdx = ei + NE;    // edge_index[1]
  float* out = (float*)d_out;

  char* wsp = (char*)d_ws;
  size_t off = 0;
  auto alloc = [&](size_t bytes)->void*{
    void* p = wsp + off;
    off = (off + bytes + 255) & ~(size_t)255;
    return p;
  };
  int* counts    = (int*)alloc((size_t)NN*sizeof(int));
  int* rowstart  = (int*)alloc((size_t)(NN+1)*sizeof(int));
  int* cursor    = (int*)alloc((size_t)NN*sizeof(int));
  int* blocksums = (int*)alloc(64*sizeof(int));
  int* blockoff  = (int*)alloc(64*sizeof(int));
  int* ssrc      = (int*)alloc((size_t)NE*sizeof(int));
  float* h1      = (float*)alloc((size_t)NN*HIDF*sizeof(float));
  float* as1     = (float*)alloc((size_t)NN*sizeof(float));
  float* ad1     = (float*)alloc((size_t)NN*sizeof(float));
  float* r1      = (float*)alloc((size_t)NN*HIDF*sizeof(float));
  // layer-2 buffers alias layer-1 buffers that are dead after k_agg1
  float* h2  = h1;     // 50000*32 floats <= 50000*64 floats
  float* as2 = as1;
  float* ad2 = ad1;

  // CSR build (per launch — ws is re-poisoned every call)
  k_zero   <<<(NN+255)/256, 256, 0, stream>>>(counts);
  k_hist   <<<(NE+255)/256, 256, 0, stream>>>(dstIdx, counts);
  k_scan_a <<<(NN+1023)/1024, 256, 0, stream>>>(counts, rowstart, blocksums);
  k_scan_b <<<1, 64, 0, stream>>>(blocksums, blockoff);
  k_scan_c <<<(NN+255)/256, 256, 0, stream>>>(counts, rowstart, blockoff, cursor);
  k_scatter<<<(NE+255)/256, 256, 0, stream>>>(srcIdx, dstIdx, cursor, ssrc);

  // layer 1
  k_gemm1<<<(NN+31)/32, 64, 0, stream>>>(x, W1, a1s, a1d, h1, as1, ad1);
  k_agg1 <<<NN/4, 256, 0, stream>>>(h1, as1, ad1, rowstart, ssrc, r1);

  // layer 2
  k_gemm2<<<(NN+31)/32, 64, 0, stream>>>(r1, W2, a2s, a2d, h2, as2, ad2);
  k_agg2 <<<NN/8, 256, 0, stream>>>(h2, as2, ad2, rowstart, ssrc, out);
}